// Round 5
// baseline (251.724 us; speedup 1.0000x reference)
//
#include <hip/hip_runtime.h>

// RBF layer, algebraically collapsed:
//   out[n,o] = Bo[o] - x2[n]*S1[o] + 2 * sum_d x[n,d] * M[d,o]
// where (all tiny, precomputed per launch from the constant inputs):
//   s[d]  = relu(sigma[d]);  w[k] = relu(width[k]);  Wr = relu(output_weights)
//   M[d,o]  = s[d] * sum_k center[k,d]*w[k]*Wr[1+k,o]          [256 x 128]
//   S1[o]   = sum_k w[k]*Wr[1+k,o]
//   c2[k]   = sum_d center[k,d]^2 * s[d]
//   Bo[o]   = Wr[0,o] + sum_k Wr[1+k,o] - sum_k c2[k]*w[k]*Wr[1+k,o]
//   x2[n]   = sum_d s[d]*x[n,d]^2   (fp32, in main kernel)
// GEMM term: bf16 MFMA 16x16x32 (abs-err ~0.1 vs threshold ~1075).
//
// Evidence log:
//  R2: nontemporal stores -> +10% WRITE_SIZE. Plain stores.
//  R3: __launch_bounds__(512,3) -> VGPR cap ~170 -> scratch spill (+600 MB
//      HBM traffic). (512,2) is the safe budget.
//  R4: LDS-staged Mfrag, one-shot grid: main still ~80 us. Diagnosis: bursts
//      issued BEFORE __syncthreads -> barrier's vmcnt(0) drain serializes
//      load-phase/compute-phase per block generation; 2 generations, no
//      cross-generation overlap.
//  R5: barrier BEFORE the bursts (drains only 17 KB staging); both tiles'
//      bursts issued back-to-back; all small constants (sigmaRelu, Bo, S1)
//      in LDS so no late VMEM forces an early full vmcnt drain.

typedef short  short8 __attribute__((ext_vector_type(8)));
typedef __bf16 bf16x8 __attribute__((ext_vector_type(8)));
typedef float  f32x4  __attribute__((ext_vector_type(4)));

#define N_ 131072
#define D_ 256
#define K_ 256
#define O_ 128

__device__ __forceinline__ unsigned short f2bf_bits(float f) {
  unsigned u = __builtin_bit_cast(unsigned, f);
  u += 0x7fffu + ((u >> 16) & 1u);   // round-to-nearest-even
  return (unsigned short)(u >> 16);
}

__device__ __forceinline__ float relu(float v) { return v > 0.f ? v : 0.f; }

// ---- Precompute kernel: 65 blocks x 256 threads ---------------------------
// Blocks 0..63: one (ks,ot) B-fragment tile of M each (32 d x 16 o); inputs
// staged in LDS so the 256-deep k-loop is pure LDS.
// Block 64: c2 -> LDS, then Bo[o], S1[o], and sigmaRelu[d].
__global__ __launch_bounds__(256) void rbf_pre(
    const float* __restrict__ center, const float* __restrict__ sigma,
    const float* __restrict__ width,  const float* __restrict__ W,
    short* __restrict__ Mfrag, float* __restrict__ Bo, float* __restrict__ S1,
    float* __restrict__ SR)
{
  const int tid = threadIdx.x;
  if (blockIdx.x < 64) {
    const int ot = blockIdx.x & 7;
    const int ks = blockIdx.x >> 3;
    __shared__ float ww[K_][16];   // 16 KB
    __shared__ float cen[K_][32];  // 32 KB
#pragma unroll
    for (int i = 0; i < 16; ++i) {
      const int k  = i * 16 + (tid >> 4);
      const int oc = tid & 15;
      ww[k][oc] = relu(width[k]) * relu(W[(1 + k) * O_ + ot * 16 + oc]);
    }
#pragma unroll
    for (int i = 0; i < 32; ++i) {
      const int k  = i * 8 + (tid >> 5);
      const int dc = tid & 31;
      cen[k][dc] = center[k * D_ + ks * 32 + dc];
    }
    __syncthreads();
    const int j   = tid & 7;
    const int lf  = tid >> 3;              // 0..31 == MFMA lane field
    const int oc  = lf & 15;
    const int dc1 = (lf >> 4) * 8 + j;     // 0..15
    float a1 = 0.f, a2 = 0.f;
#pragma unroll 8
    for (int k = 0; k < K_; ++k) {
      const float w = ww[k][oc];
      a1 = fmaf(cen[k][dc1],      w, a1);
      a2 = fmaf(cen[k][dc1 + 16], w, a2);
    }
    const int e1 = blockIdx.x * 512 + tid;
    const int d1 = ks * 32 + dc1;
    Mfrag[e1]       = (short)f2bf_bits(a1 * relu(sigma[d1]));
    Mfrag[e1 + 256] = (short)f2bf_bits(a2 * relu(sigma[d1 + 16]));
  } else {
    __shared__ float c2s[K_];
    SR[tid] = relu(sigma[tid]);            // 256 floats for the main kernel
    {
      const f32x4* cr = (const f32x4*)(center + tid * D_);
      const f32x4* sr = (const f32x4*)sigma;
      f32x4 acc = {0.f, 0.f, 0.f, 0.f};
#pragma unroll 8
      for (int d4 = 0; d4 < D_ / 4; ++d4) {
        const f32x4 c = cr[d4];
        const f32x4 s = sr[d4];
#pragma unroll
        for (int e = 0; e < 4; ++e) acc[e] = fmaf(c[e] * c[e], relu(s[e]), acc[e]);
      }
      c2s[tid] = (acc[0] + acc[1]) + (acc[2] + acc[3]);
    }
    __syncthreads();
    if (tid < O_) {
      const int o = tid;
      float s1 = 0.f, sum = 0.f, c2w = 0.f;
#pragma unroll 4
      for (int k = 0; k < K_; ++k) {
        const float w  = relu(width[k]);
        const float wr = relu(W[(1 + k) * O_ + o]);
        s1  = fmaf(w, wr, s1);
        sum += wr;
        c2w = fmaf(c2s[k] * w, wr, c2w);
      }
      Bo[o] = relu(W[o]) + sum - c2w;
      S1[o] = s1;
    }
  }
}

// ---- Main kernel: 512 blocks x 512 threads (8 waves), 2 tiles/wave --------
// Single early barrier (staging only); both tiles' x bursts issued together
// afterwards so tile-1 loads stream in under tile-0 compute (vmcnt(16), never
// a full drain). All constants in LDS. (512,2): no spill (R3 lesson).
__global__ __launch_bounds__(512, 2) void rbf_main(
    const float* __restrict__ x, const short* __restrict__ Mfrag,
    const float* __restrict__ SR, const float* __restrict__ Bo,
    const float* __restrict__ S1, float* __restrict__ out)
{
  __shared__ short8 Blds[4096];   // 64 KiB, B-fragment layout
  __shared__ float  sigL[256];    // relu(sigma)
  __shared__ float  BoL[128];
  __shared__ float  S1L[128];

  const int tid  = threadIdx.x;
  const int lane = tid & 63;
  const int wv   = tid >> 6;                    // 0..7
  const int m    = lane & 15;                   // A row / C col within tile
  const int q    = lane >> 4;                   // quad

  // ---- stage all constants into LDS (the ONLY VMEM before the barrier) ----
  {
    const short8* Mf8 = (const short8*)Mfrag;
    short8 stg[8];
#pragma unroll
    for (int i = 0; i < 8; ++i) stg[i] = Mf8[i * 512 + tid];
#pragma unroll
    for (int i = 0; i < 8; ++i) Blds[i * 512 + tid] = stg[i];
    if (tid < 64)       ((f32x4*)sigL)[tid]     = ((const f32x4*)SR)[tid];
    else if (tid < 96)  ((f32x4*)BoL)[tid - 64] = ((const f32x4*)Bo)[tid - 64];
    else if (tid < 128) ((f32x4*)S1L)[tid - 96] = ((const f32x4*)S1)[tid - 96];
  }
  __syncthreads();   // drains only ~17 KB/block of L2-hot staging

  const long t0 = (long)blockIdx.x * 8 + wv;    // 0..4095
  const long r0 = t0 * 16;
  const long r1 = (t0 + 4096) * 16;
  const float* xr0 = x + (r0 + m) * D_ + q * 8;
  const float* xr1 = x + (r1 + m) * D_ + q * 8;

  // Issue BOTH tiles' bursts back-to-back: 32 dwordx4 in flight per lane.
  f32x4 raw0[16], raw1[16];
#pragma unroll
  for (int ks = 0; ks < 8; ++ks) {
    raw0[2 * ks]     = *(const f32x4*)(xr0 + ks * 32);
    raw0[2 * ks + 1] = *(const f32x4*)(xr0 + ks * 32 + 4);
  }
#pragma unroll
  for (int ks = 0; ks < 8; ++ks) {
    raw1[2 * ks]     = *(const f32x4*)(xr1 + ks * 32);
    raw1[2 * ks + 1] = *(const f32x4*)(xr1 + ks * 32 + 4);
  }

  // Per-lane epilogue constants (LDS broadcasts, conflict-free).
  float bo8[8], s18[8];
#pragma unroll
  for (int ot = 0; ot < 8; ++ot) {
    bo8[ot] = BoL[ot * 16 + m];
    s18[ot] = S1L[ot * 16 + m];
  }

  auto process = [&](const f32x4 (&raw)[16], long rowBase) {
    bf16x8 a[8];
    float x2 = 0.f;
#pragma unroll
    for (int ks = 0; ks < 8; ++ks) {
      float sv[8], v[8];
      *(f32x4*)(sv)     = *(const f32x4*)(sigL + ks * 32 + q * 8);     // relu'd
      *(f32x4*)(sv + 4) = *(const f32x4*)(sigL + ks * 32 + q * 8 + 4);
      *(f32x4*)(v)      = raw[2 * ks];
      *(f32x4*)(v + 4)  = raw[2 * ks + 1];
      short8 ab;
#pragma unroll
      for (int jj = 0; jj < 8; ++jj) {
        x2 = fmaf(sv[jj] * v[jj], v[jj], x2);
        ab[jj] = (short)f2bf_bits(v[jj]);
      }
      a[ks] = __builtin_bit_cast(bf16x8, ab);
    }
    // Full-row x2: lanes m, m+16, m+32, m+48 hold partials of row rowBase+m.
    x2 += __shfl_xor(x2, 16);
    x2 += __shfl_xor(x2, 32);
    // Broadcast once (4 bpermutes, not 32): xb[r] = x2 of row q*4+r.
    float xb[4];
#pragma unroll
    for (int r = 0; r < 4; ++r) xb[r] = __shfl(x2, q * 4 + r);

#pragma unroll
    for (int ot = 0; ot < 8; ++ot) {
      f32x4 acc = {0.f, 0.f, 0.f, 0.f};
#pragma unroll
      for (int ks = 0; ks < 8; ++ks) {
        const bf16x8 bb =
            __builtin_bit_cast(bf16x8, Blds[(ks * 8 + ot) * 64 + lane]);
        acc = __builtin_amdgcn_mfma_f32_16x16x32_bf16(a[ks], bb, acc, 0, 0, 0);
      }
      float* op = out + rowBase * O_ + ot * 16 + m;   // C/D: col = lane&15
#pragma unroll
      for (int r = 0; r < 4; ++r)                     // row = q*4 + r
        op[(long)(q * 4 + r) * O_] =
            fmaf(2.f, acc[r], fmaf(-xb[r], s18[ot], bo8[ot]));
    }
  };

  process(raw0, r0);   // waits vmcnt(16): raw1 stays in flight
  process(raw1, r1);   // raw1 landed during tile-0 compute
}

extern "C" void kernel_launch(void* const* d_in, const int* in_sizes, int n_in,
                              void* d_out, int out_size, void* d_ws, size_t ws_size,
                              hipStream_t stream) {
  (void)in_sizes; (void)n_in; (void)out_size; (void)ws_size;
  const float* x      = (const float*)d_in[0];
  const float* center = (const float*)d_in[1];
  const float* sigma  = (const float*)d_in[2];
  const float* width  = (const float*)d_in[3];
  const float* W      = (const float*)d_in[4];
  float* out = (float*)d_out;

  short* Mfrag = (short*)d_ws;                       // 64 KiB
  float* Bo    = (float*)((char*)d_ws + 65536);      // 512 B
  float* S1    = (float*)((char*)d_ws + 66048);      // 512 B
  float* SR    = (float*)((char*)d_ws + 66560);      // 1 KiB

  hipLaunchKernelGGL(rbf_pre, dim3(65), dim3(256), 0, stream,
                     center, sigma, width, W, Mfrag, Bo, S1, SR);
  hipLaunchKernelGGL(rbf_main, dim3(512), dim3(512), 0, stream,
                     x, Mfrag, SR, Bo, S1, out);
}